// Round 16
// baseline (345.305 us; speedup 1.0000x reference)
//
#include <hip/hip_runtime.h>
#include <math.h>

#define N_NODES 10000
#define E_EDGES 160000
#define E_TOT   170000   // E + self loops
#define MAXDEG  128
#define MPAD    10112    // 79 * 128

typedef _Float16 f16x8 __attribute__((ext_vector_type(8)));
typedef _Float16 f16x4 __attribute__((ext_vector_type(4)));
typedef float    f32x4 __attribute__((ext_vector_type(4)));

__device__ __forceinline__ float leaky(float e) { return (e > 0.f) ? e : 0.2f * e; }

__device__ __forceinline__ unsigned int pack_as(float a, int s) {
    union { _Float16 h; unsigned short u; } cv;
    cv.h = (_Float16)a;
    return (unsigned int)(unsigned short)s | ((unsigned int)cv.u << 16);
}

__device__ __forceinline__ float unpack_a(unsigned int p) {
    union { unsigned short u; _Float16 hf; } cv; cv.u = (unsigned short)(p >> 16);
    return (float)cv.hf;
}

// ---------------- graph CSR build (by dst) ----------------
__global__ void count_kernel(const int* __restrict__ ei, int* __restrict__ deg) {
    int e = blockIdx.x * 256 + threadIdx.x;
    if (e >= E_TOT) return;
    int dst = (e < E_EDGES) ? ei[E_EDGES + e] : (e - E_EDGES);
    atomicAdd(&deg[dst], 1);
}

__global__ void scan_kernel(const int* __restrict__ deg, int* __restrict__ rowptr,
                            int* __restrict__ cursor) {
    __shared__ int sums[1024];
    int t = threadIdx.x;
    const int CH = (N_NODES + 1023) / 1024;
    int base = t * CH;
    int s = 0;
    for (int j = 0; j < CH; j++) { int i = base + j; if (i < N_NODES) s += deg[i]; }
    sums[t] = s; __syncthreads();
    for (int off = 1; off < 1024; off <<= 1) {
        int v = (t >= off) ? sums[t - off] : 0;
        __syncthreads();
        sums[t] += v;
        __syncthreads();
    }
    int excl = (t == 0) ? 0 : sums[t - 1];
    for (int j = 0; j < CH; j++) {
        int i = base + j;
        if (i < N_NODES) { rowptr[i] = excl; cursor[i] = excl; excl += deg[i]; }
    }
    if (t == 1023) rowptr[N_NODES] = sums[1023];
}

__global__ void scatter_kernel(const int* __restrict__ ei, int* __restrict__ cursor,
                               int* __restrict__ perm_src) {
    int e = blockIdx.x * 256 + threadIdx.x;
    if (e >= E_TOT) return;
    int src, dst;
    if (e < E_EDGES) { src = ei[e]; dst = ei[E_EDGES + e]; }
    else { src = e - E_EDGES; dst = src; }
    int pos = atomicAdd(&cursor[dst], 1);
    perm_src[pos] = src;
}

// ---------------- all conversions / padding in one kernel ----------------
#define SEG0 (MPAD * 64)               // xh1
#define SEG1 (1024 * 64)               // W1h
#define SEG2 (1024 * 1024)             // W2h
#define SEG3 (768 * 1024)              // W3p (head-padded rows)
#define SEG4 768                        // asp/adp
#define SEG5 ((MPAD - N_NODES) * 1024) // xh zero tail
#define CVT_TOTAL (SEG0 + SEG1 + SEG2 + SEG3 + SEG4 + SEG5)

__global__ void cvt_all(const float* __restrict__ x, const float* __restrict__ W1,
                        const float* __restrict__ W2, const float* __restrict__ W3,
                        const float* __restrict__ as3, const float* __restrict__ ad3,
                        _Float16* __restrict__ xh1, _Float16* __restrict__ W1h,
                        _Float16* __restrict__ W2h, _Float16* __restrict__ W3p,
                        float* __restrict__ asp, float* __restrict__ adp,
                        _Float16* __restrict__ xh) {
    int i = blockIdx.x * 256 + threadIdx.x;
    if (i < SEG0) {
        int r = i >> 6, c = i & 63;
        xh1[i] = (r < N_NODES && c < 50) ? (_Float16)x[r * 50 + c] : (_Float16)0.f;
        return;
    }
    i -= SEG0;
    if (i < SEG1) {
        int r = i >> 6, c = i & 63;
        W1h[i] = (c < 50) ? (_Float16)W1[r * 50 + c] : (_Float16)0.f;
        return;
    }
    i -= SEG1;
    if (i < SEG2) { W2h[i] = (_Float16)W2[i]; return; }
    i -= SEG2;
    if (i < SEG3) {
        int r = i >> 10, k = i & 1023;
        int hh = r >> 7, cc = r & 127;
        W3p[i] = (cc < 121) ? (_Float16)W3[(size_t)(hh * 121 + cc) * 1024 + k] : (_Float16)0.f;
        return;
    }
    i -= SEG3;
    if (i < SEG4) {
        int hh = i >> 7, cc = i & 127;
        asp[i] = (cc < 121) ? as3[hh * 121 + cc] : 0.f;
        adp[i] = (cc < 121) ? ad3[hh * 121 + cc] : 0.f;
        return;
    }
    i -= SEG4;
    if (i < SEG5) xh[N_NODES * 1024 + i] = (_Float16)0.f;
}

// ---------------- fp16 MFMA GEMM with XCD-local row-panel mapping ----------------
__device__ __forceinline__ void gload_lds(const _Float16* g, _Float16* l) {
    __builtin_amdgcn_global_load_lds(
        (const __attribute__((address_space(1))) void*)g,
        (__attribute__((address_space(3))) void*)l, 16, 0, 0);
}

__global__ __launch_bounds__(256) void gemm_mfma(const _Float16* __restrict__ A,
                                                 const _Float16* __restrict__ B,
                                                 _Float16* __restrict__ C,
                                                 int M, int Nn, int Kp, int ldc) {
    const int NXB = gridDim.y / 10;
    const int rb  = blockIdx.x + 8 * (blockIdx.y / NXB);
    const int cb  = blockIdx.y % NXB;
    if (rb >= 79) return;
    __shared__ _Float16 lds[16384];
    const int tid  = threadIdx.x;
    const int bm   = rb * 128, bn = cb * 128;
    const int w    = tid >> 6, lane = tid & 63;
    const int wr   = w >> 1,   wc   = w & 1;
    const int la   = lane & 15, g = lane >> 4;

    f32x4 acc[4][4] = {};

    const int srow = tid >> 3;
    const int skb0 = (tid & 7) * 16;

    for (int k0 = 0; k0 < Kp; k0 += 64) {
        __syncthreads();
#pragma unroll
        for (int i = 0; i < 4; i++) {
            int row = i * 32 + srow;
            int kb  = skb0 ^ ((row & 7) << 4);
            gload_lds(A + (size_t)(bm + row) * Kp + k0 + (kb >> 1),
                      lds + i * 2048 + w * 512);
        }
#pragma unroll
        for (int i = 0; i < 4; i++) {
            int row = i * 32 + srow;
            int kb  = skb0 ^ ((row & 7) << 4);
            gload_lds(B + (size_t)(bn + row) * Kp + k0 + (kb >> 1),
                      lds + 8192 + i * 2048 + w * 512);
        }
        asm volatile("s_waitcnt vmcnt(0)");
        __syncthreads();
#pragma unroll
        for (int s = 0; s < 2; s++) {
            f16x8 af[4], bf[4];
#pragma unroll
            for (int m = 0; m < 4; m++) {
                int r  = wr * 64 + m * 16 + la;
                int bc = (s * 64 + g * 16) ^ ((r & 7) << 4);
                af[m] = *(const f16x8*)(lds + r * 64 + (bc >> 1));
            }
#pragma unroll
            for (int n = 0; n < 4; n++) {
                int r  = wc * 64 + n * 16 + la;
                int bc = (s * 64 + g * 16) ^ ((r & 7) << 4);
                bf[n] = *(const f16x8*)(lds + 8192 + r * 64 + (bc >> 1));
            }
#pragma unroll
            for (int m = 0; m < 4; m++)
#pragma unroll
                for (int n = 0; n < 4; n++)
                    acc[m][n] = __builtin_amdgcn_mfma_f32_16x16x32_f16(af[m], bf[n], acc[m][n], 0, 0, 0);
        }
    }
#pragma unroll
    for (int m = 0; m < 4; m++) {
#pragma unroll
        for (int n = 0; n < 4; n++) {
            int col = bn + wc * 64 + n * 16 + la;
            if (col >= Nn) continue;
#pragma unroll
            for (int r = 0; r < 4; r++) {
                int row = bm + wr * 64 + m * 16 + g * 4 + r;
                if (row < M) C[(size_t)row * ldc + col] = (_Float16)acc[m][n][r];
            }
        }
    }
}

// ---------------- attn for H=4, HC=1024: one wave per node ----------------
__global__ __launch_bounds__(256) void attn4(const _Float16* __restrict__ h,
        const float* __restrict__ a_s, const float* __restrict__ a_d,
        float* __restrict__ esrc, float* __restrict__ edst) {
    const int w = threadIdx.x >> 6, lane = threadIdx.x & 63;
    const int node = blockIdx.x * 4 + w;
    const _Float16* row = h + (size_t)node * 1024;
    float ps[4], pd[4];
#pragma unroll
    for (int j = 0; j < 4; j++) {
        int c0 = j * 256 + lane * 4;
        f16x4 v = *(const f16x4*)(row + c0);
        float4 sa = *(const float4*)(a_s + c0);
        float4 da = *(const float4*)(a_d + c0);
        ps[j] = (float)v[0] * sa.x + (float)v[1] * sa.y + (float)v[2] * sa.z + (float)v[3] * sa.w;
        pd[j] = (float)v[0] * da.x + (float)v[1] * da.y + (float)v[2] * da.z + (float)v[3] * da.w;
    }
#pragma unroll
    for (int j = 0; j < 4; j++) {
#pragma unroll
        for (int off = 32; off; off >>= 1) {
            ps[j] += __shfl_xor(ps[j], off);
            pd[j] += __shfl_xor(pd[j], off);
        }
    }
    if (lane == 0) {
        *(float4*)(esrc + (size_t)node * 4) = make_float4(ps[0], ps[1], ps[2], ps[3]);
        *(float4*)(edst + (size_t)node * 4) = make_float4(pd[0], pd[1], pd[2], pd[3]);
    }
}

// ---------------- attn for layer 3 (padded head stride 128): one wave per node ----------------
__global__ __launch_bounds__(256) void attn6(const _Float16* __restrict__ h,
        const float* __restrict__ asp, const float* __restrict__ adp,
        float* __restrict__ esrc, float* __restrict__ edst) {
    const int w = threadIdx.x >> 6, lane = threadIdx.x & 63;
    const int node = blockIdx.x * 4 + w;
    const _Float16* row = h + (size_t)node * 768;
    float ps[3], pd[3];
#pragma unroll
    for (int j = 0; j < 3; j++) {
        int c0 = j * 256 + lane * 4;   // head = 2j + (lane>=32)
        f16x4 v = *(const f16x4*)(row + c0);
        float4 sa = *(const float4*)(asp + c0);
        float4 da = *(const float4*)(adp + c0);
        ps[j] = (float)v[0] * sa.x + (float)v[1] * sa.y + (float)v[2] * sa.z + (float)v[3] * sa.w;
        pd[j] = (float)v[0] * da.x + (float)v[1] * da.y + (float)v[2] * da.z + (float)v[3] * da.w;
    }
#pragma unroll
    for (int j = 0; j < 3; j++) {
#pragma unroll
        for (int off = 16; off; off >>= 1) {
            ps[j] += __shfl_xor(ps[j], off);
            pd[j] += __shfl_xor(pd[j], off);
        }
    }
    if (lane == 0 || lane == 32) {
        int hb = lane >> 5;
        float* es = esrc + (size_t)node * 6;
        float* ed = edst + (size_t)node * 6;
#pragma unroll
        for (int j = 0; j < 3; j++) { es[2 * j + hb] = ps[j]; ed[2 * j + hb] = pd[j]; }
    }
}

// ---------------- softmax alphas: wave per dst, SoA packed {src:u16, alpha:f16} ----------------
template<int H>
__global__ __launch_bounds__(256) void alpha_kernel(const float* __restrict__ esrc,
        const float* __restrict__ edst, const int* __restrict__ rowptr,
        const int* __restrict__ perm, unsigned int* __restrict__ pack) {
    const int w = threadIdx.x >> 6, lane = threadIdx.x & 63;
    const int d = blockIdx.x * 4 + w;
    int r0 = rowptr[d];
    int deg = rowptr[d + 1] - r0; if (deg > MAXDEG) deg = MAXDEG;
    float ed[H];
#pragma unroll
    for (int j = 0; j < H; j++) ed[j] = edst[(size_t)d * H + j];
    int s0 = 0, s1 = 0;
    float e0[H], e1[H];
    const bool a0v = lane < deg, a1v = lane + 64 < deg;
    if (a0v) {
        s0 = perm[r0 + lane];
        const float* pe = esrc + (size_t)s0 * H;
#pragma unroll
        for (int j = 0; j < H; j++) e0[j] = leaky(pe[j] + ed[j]);
    }
    if (a1v) {
        s1 = perm[r0 + lane + 64];
        const float* pe = esrc + (size_t)s1 * H;
#pragma unroll
        for (int j = 0; j < H; j++) e1[j] = leaky(pe[j] + ed[j]);
    }
#pragma unroll
    for (int j = 0; j < H; j++) {
        float m = fmaxf(a0v ? e0[j] : -1e30f, a1v ? e1[j] : -1e30f);
#pragma unroll
        for (int off = 32; off; off >>= 1) m = fmaxf(m, __shfl_xor(m, off));
        float x0 = a0v ? __expf(e0[j] - m) : 0.f;
        float x1 = a1v ? __expf(e1[j] - m) : 0.f;
        float ss = x0 + x1;
#pragma unroll
        for (int off = 32; off; off >>= 1) ss += __shfl_xor(ss, off);
        float inv = 1.f / fmaxf(ss, 1e-16f);
        e0[j] = x0 * inv; e1[j] = x1 * inv;
    }
    if (a0v) {
#pragma unroll
        for (int j = 0; j < H; j++) pack[(size_t)j * E_TOT + r0 + lane] = pack_as(e0[j], s0);
    }
    if (a1v) {
#pragma unroll
        for (int j = 0; j < H; j++) pack[(size_t)j * E_TOT + r0 + lane + 64] = pack_as(e1[j], s1);
    }
}

// ---------------- XCD-sliced gather v7: round-12 structure + non-temporal streams ----------
// grid(8, 313): 16 lanes x f16x8 per dst, 4 par x 2 ser dsts/wave. Streaming accesses
// (pack, xh residual, xh/obuf writes) are non-temporal so the h-slice stays L2-resident.
template<int RES>
__global__ __launch_bounds__(256) void agg_slice2(const _Float16* __restrict__ h,
        const unsigned int* __restrict__ pack, const int* __restrict__ rowptr,
        const float* __restrict__ bias, _Float16* __restrict__ xh) {
    const int s = blockIdx.x;
    const int w = threadIdx.x >> 6, lane = threadIdx.x & 63;
    const int g = lane >> 4, sl = lane & 15;
    const int col = s * 128 + sl * 8;
    const int hh = s >> 1;
    const unsigned int* packh = pack + (size_t)hh * E_TOT;
    f32x4 bv0 = *(const f32x4*)(bias + col);
    f32x4 bv1 = *(const f32x4*)(bias + col + 4);
    const int dbase = blockIdx.y * 32 + w * 8 + g;
#pragma unroll
    for (int it = 0; it < 2; it++) {
        const int d = dbase + it * 4;
        if (d >= N_NODES) continue;
        int r0 = rowptr[d];
        int deg = rowptr[d + 1] - r0; if (deg > MAXDEG) deg = MAXDEG;
        const unsigned int* pp = packh + r0;
        float acc[8] = {};
#pragma unroll 4
        for (int t = 0; t < deg; t++) {
            unsigned int p = __builtin_nontemporal_load(pp + t);
            float a = unpack_a(p);
            f16x8 v = *(const f16x8*)(h + (size_t)(p & 0xFFFF) * 1024 + col);
#pragma unroll
            for (int j = 0; j < 8; j++) acc[j] = fmaf(a, (float)v[j], acc[j]);
        }
        size_t o = (size_t)d * 1024 + col;
        float vv[8];
        vv[0] = acc[0] + bv0[0]; vv[1] = acc[1] + bv0[1];
        vv[2] = acc[2] + bv0[2]; vv[3] = acc[3] + bv0[3];
        vv[4] = acc[4] + bv1[0]; vv[5] = acc[5] + bv1[1];
        vv[6] = acc[6] + bv1[2]; vv[7] = acc[7] + bv1[3];
        if (RES) {
            f16x8 rv = __builtin_nontemporal_load((const f16x8*)(xh + o));
#pragma unroll
            for (int j = 0; j < 8; j++) vv[j] += (float)rv[j];
        }
        f16x8 hv;
#pragma unroll
        for (int j = 0; j < 8; j++) {
            float u = vv[j];
            u = (u > 0.f) ? u : expm1f(u);
            hv[j] = (_Float16)u;
        }
        __builtin_nontemporal_store(hv, (f16x8*)(xh + o));
    }
}

// ---------------- layer-3 sliced gather: grid(8,313), slices 6,7 idle, nt streams --------
__global__ __launch_bounds__(256) void agg_slice3(const _Float16* __restrict__ h,
        const unsigned int* __restrict__ pack, const int* __restrict__ rowptr,
        _Float16* __restrict__ obuf) {
    const int s = blockIdx.x;               // == head; 6,7 idle
    if (s >= 6) return;
    const int w = threadIdx.x >> 6, lane = threadIdx.x & 63;
    const int g = lane >> 4, sl = lane & 15;
    const int col = s * 128 + sl * 8;
    const unsigned int* packh = pack + (size_t)s * E_TOT;
    const int dbase = blockIdx.y * 32 + w * 8 + g;
#pragma unroll
    for (int it = 0; it < 2; it++) {
        const int d = dbase + it * 4;
        if (d >= N_NODES) continue;
        int r0 = rowptr[d];
        int deg = rowptr[d + 1] - r0; if (deg > MAXDEG) deg = MAXDEG;
        const unsigned int* pp = packh + r0;
        float acc[8] = {};
#pragma unroll 4
        for (int t = 0; t < deg; t++) {
            unsigned int p = __builtin_nontemporal_load(pp + t);
            float a = unpack_a(p);
            f16x8 v = *(const f16x8*)(h + (size_t)(p & 0xFFFF) * 768 + col);
#pragma unroll
            for (int j = 0; j < 8; j++) acc[j] = fmaf(a, (float)v[j], acc[j]);
        }
        f16x8 hv;
#pragma unroll
        for (int j = 0; j < 8; j++) hv[j] = (_Float16)acc[j];
        __builtin_nontemporal_store(hv, (f16x8*)(obuf + (size_t)d * 768 + col));
    }
}

// ---------------- final head-mean + bias + sigmoid ----------------
__global__ void finish_kernel(const _Float16* __restrict__ obuf,
                              const float* __restrict__ b3, float* __restrict__ out) {
    int i = blockIdx.x * 256 + threadIdx.x;
    if (i >= N_NODES * 121) return;
    int d = i / 121, cc = i - d * 121;
    float ssum = 0.f;
#pragma unroll
    for (int hh = 0; hh < 6; hh++) ssum += (float)obuf[(size_t)d * 768 + hh * 128 + cc];
    float sres = ssum * (1.f / 6.f) + b3[cc];
    out[i] = 1.f / (1.f + __expf(-sres));
}

// ---------------- launcher ----------------
extern "C" void kernel_launch(void* const* d_in, const int* in_sizes, int n_in,
                              void* d_out, int out_size, void* d_ws, size_t ws_size,
                              hipStream_t stream) {
    const float* x   = (const float*)d_in[0];
    const int*   ei  = (const int*)d_in[1];
    const float* W1  = (const float*)d_in[2];
    const float* as1 = (const float*)d_in[3];
    const float* ad1 = (const float*)d_in[4];
    const float* b1  = (const float*)d_in[5];
    const float* W2  = (const float*)d_in[6];
    const float* as2 = (const float*)d_in[7];
    const float* ad2 = (const float*)d_in[8];
    const float* b2  = (const float*)d_in[9];
    const float* W3  = (const float*)d_in[10];
    const float* as3 = (const float*)d_in[11];
    const float* ad3 = (const float*)d_in[12];
    const float* b3  = (const float*)d_in[13];
    float* out = (float*)d_out;

    float* fws  = (float*)d_ws;
    float* esrc = fws;                       // N*6
    float* edst = fws + 60000;               // N*6
    float* asp  = fws + 120000;              // 768
    float* adp  = fws + 120768;              // 768
    unsigned int* pack = (unsigned int*)(fws + 121536);  // 6 * E_TOT u32
    int*   iws  = (int*)(fws + 121536 + 6 * E_TOT);
    int* deg    = iws;                       // N
    int* rowptr = iws + N_NODES;             // N+1
    int* cursor = iws + 2 * N_NODES + 1;     // N
    int* perm   = iws + 3 * N_NODES + 1;     // E_TOT
    _Float16* f16b = (_Float16*)(iws + 3 * N_NODES + 1 + E_TOT + 3);
    _Float16* xh   = f16b;                          // MPAD*1024
    _Float16* xh1  = xh + (size_t)MPAD * 1024;      // MPAD*64
    _Float16* W1h  = xh1 + (size_t)MPAD * 64;       // 1024*64
    _Float16* W2h  = W1h + 1024 * 64;               // 1024*1024
    _Float16* W3p  = W2h + 1024 * 1024;             // 768*1024 (head-padded)
    _Float16* h16  = W3p + 768 * 1024;              // MPAD*1024
    _Float16* obuf = h16 + (size_t)MPAD * 1024;     // N*768

    hipMemsetAsync(deg, 0, N_NODES * sizeof(int), stream);
    count_kernel<<<(E_TOT + 255) / 256, 256, 0, stream>>>(ei, deg);
    scan_kernel<<<1, 1024, 0, stream>>>(deg, rowptr, cursor);
    scatter_kernel<<<(E_TOT + 255) / 256, 256, 0, stream>>>(ei, cursor, perm);

    dim3 blk(256);
    cvt_all<<<(CVT_TOTAL + 255) / 256, blk, 0, stream>>>(x, W1, W2, W3, as3, ad3,
                                                          xh1, W1h, W2h, W3p, asp, adp, xh);

    // ---- layer 1: K=50->64, H=4, C=256 ----
    {
        gemm_mfma<<<dim3(8, 80), blk, 0, stream>>>(xh1, W1h, h16, N_NODES, 1024, 64, 1024);
        attn4<<<N_NODES / 4, blk, 0, stream>>>(h16, as1, ad1, esrc, edst);
        alpha_kernel<4><<<N_NODES / 4, blk, 0, stream>>>(esrc, edst, rowptr, perm, pack);
        agg_slice2<0><<<dim3(8, 313), blk, 0, stream>>>(h16, pack, rowptr, b1, xh);
    }
    // ---- layer 2: K=1024, H=4, C=256, residual ----
    {
        gemm_mfma<<<dim3(8, 80), blk, 0, stream>>>(xh, W2h, h16, N_NODES, 1024, 1024, 1024);
        attn4<<<N_NODES / 4, blk, 0, stream>>>(h16, as2, ad2, esrc, edst);
        alpha_kernel<4><<<N_NODES / 4, blk, 0, stream>>>(esrc, edst, rowptr, perm, pack);
        agg_slice2<1><<<dim3(8, 313), blk, 0, stream>>>(h16, pack, rowptr, b2, xh);
    }
    // ---- layer 3: K=1024, H=6, C=121 (padded 128), mean heads + sigmoid ----
    {
        gemm_mfma<<<dim3(8, 60), blk, 0, stream>>>(xh, W3p, h16, N_NODES, 768, 1024, 768);
        attn6<<<N_NODES / 4, blk, 0, stream>>>(h16, asp, adp, esrc, edst);
        alpha_kernel<6><<<N_NODES / 4, blk, 0, stream>>>(esrc, edst, rowptr, perm, pack);
        agg_slice3<<<dim3(8, 313), blk, 0, stream>>>(h16, pack, rowptr, obuf);
        finish_kernel<<<(N_NODES * 121 + 255) / 256, blk, 0, stream>>>(obuf, b3, out);
    }
}

// Round 17
// 290.374 us; speedup vs baseline: 1.1892x; 1.1892x over previous
//
#include <hip/hip_runtime.h>
#include <math.h>

#define N_NODES 10000
#define E_EDGES 160000
#define E_TOT   170000   // E + self loops
#define MAXDEG  128
#define MPAD    10112    // 79 * 128

typedef _Float16 f16x8 __attribute__((ext_vector_type(8)));
typedef _Float16 f16x4 __attribute__((ext_vector_type(4)));
typedef float    f32x4 __attribute__((ext_vector_type(4)));

__device__ __forceinline__ float leaky(float e) { return (e > 0.f) ? e : 0.2f * e; }

__device__ __forceinline__ unsigned int pack_as(float a, int s) {
    union { _Float16 h; unsigned short u; } cv;
    cv.h = (_Float16)a;
    return (unsigned int)(unsigned short)s | ((unsigned int)cv.u << 16);
}

__device__ __forceinline__ float unpack_a(unsigned int p) {
    union { unsigned short u; _Float16 hf; } cv; cv.u = (unsigned short)(p >> 16);
    return (float)cv.hf;
}

// ---------------- graph CSR build (by dst) ----------------
__global__ void count_kernel(const int* __restrict__ ei, int* __restrict__ deg) {
    int e = blockIdx.x * 256 + threadIdx.x;
    if (e >= E_TOT) return;
    int dst = (e < E_EDGES) ? ei[E_EDGES + e] : (e - E_EDGES);
    atomicAdd(&deg[dst], 1);
}

__global__ void scan_kernel(const int* __restrict__ deg, int* __restrict__ rowptr,
                            int* __restrict__ cursor) {
    __shared__ int sums[1024];
    int t = threadIdx.x;
    const int CH = (N_NODES + 1023) / 1024;
    int base = t * CH;
    int s = 0;
    for (int j = 0; j < CH; j++) { int i = base + j; if (i < N_NODES) s += deg[i]; }
    sums[t] = s; __syncthreads();
    for (int off = 1; off < 1024; off <<= 1) {
        int v = (t >= off) ? sums[t - off] : 0;
        __syncthreads();
        sums[t] += v;
        __syncthreads();
    }
    int excl = (t == 0) ? 0 : sums[t - 1];
    for (int j = 0; j < CH; j++) {
        int i = base + j;
        if (i < N_NODES) { rowptr[i] = excl; cursor[i] = excl; excl += deg[i]; }
    }
    if (t == 1023) rowptr[N_NODES] = sums[1023];
}

__global__ void scatter_kernel(const int* __restrict__ ei, int* __restrict__ cursor,
                               int* __restrict__ perm_src) {
    int e = blockIdx.x * 256 + threadIdx.x;
    if (e >= E_TOT) return;
    int src, dst;
    if (e < E_EDGES) { src = ei[e]; dst = ei[E_EDGES + e]; }
    else { src = e - E_EDGES; dst = src; }
    int pos = atomicAdd(&cursor[dst], 1);
    perm_src[pos] = src;
}

// ---------------- all conversions / padding in one kernel ----------------
#define SEG0 (MPAD * 64)               // xh1
#define SEG1 (1024 * 64)               // W1h
#define SEG2 (1024 * 1024)             // W2h
#define SEG3 (768 * 1024)              // W3p (head-padded rows)
#define SEG4 768                        // asp/adp
#define SEG5 ((MPAD - N_NODES) * 1024) // xh zero tail
#define CVT_TOTAL (SEG0 + SEG1 + SEG2 + SEG3 + SEG4 + SEG5)

__global__ void cvt_all(const float* __restrict__ x, const float* __restrict__ W1,
                        const float* __restrict__ W2, const float* __restrict__ W3,
                        const float* __restrict__ as3, const float* __restrict__ ad3,
                        _Float16* __restrict__ xh1, _Float16* __restrict__ W1h,
                        _Float16* __restrict__ W2h, _Float16* __restrict__ W3p,
                        float* __restrict__ asp, float* __restrict__ adp,
                        _Float16* __restrict__ xh) {
    int i = blockIdx.x * 256 + threadIdx.x;
    if (i < SEG0) {
        int r = i >> 6, c = i & 63;
        xh1[i] = (r < N_NODES && c < 50) ? (_Float16)x[r * 50 + c] : (_Float16)0.f;
        return;
    }
    i -= SEG0;
    if (i < SEG1) {
        int r = i >> 6, c = i & 63;
        W1h[i] = (c < 50) ? (_Float16)W1[r * 50 + c] : (_Float16)0.f;
        return;
    }
    i -= SEG1;
    if (i < SEG2) { W2h[i] = (_Float16)W2[i]; return; }
    i -= SEG2;
    if (i < SEG3) {
        int r = i >> 10, k = i & 1023;
        int hh = r >> 7, cc = r & 127;
        W3p[i] = (cc < 121) ? (_Float16)W3[(size_t)(hh * 121 + cc) * 1024 + k] : (_Float16)0.f;
        return;
    }
    i -= SEG3;
    if (i < SEG4) {
        int hh = i >> 7, cc = i & 127;
        asp[i] = (cc < 121) ? as3[hh * 121 + cc] : 0.f;
        adp[i] = (cc < 121) ? ad3[hh * 121 + cc] : 0.f;
        return;
    }
    i -= SEG4;
    if (i < SEG5) xh[N_NODES * 1024 + i] = (_Float16)0.f;
}

// ---------------- fp16 MFMA GEMM with XCD-local row-panel mapping ----------------
__device__ __forceinline__ void gload_lds(const _Float16* g, _Float16* l) {
    __builtin_amdgcn_global_load_lds(
        (const __attribute__((address_space(1))) void*)g,
        (__attribute__((address_space(3))) void*)l, 16, 0, 0);
}

__global__ __launch_bounds__(256) void gemm_mfma(const _Float16* __restrict__ A,
                                                 const _Float16* __restrict__ B,
                                                 _Float16* __restrict__ C,
                                                 int M, int Nn, int Kp, int ldc) {
    const int NXB = gridDim.y / 10;
    const int rb  = blockIdx.x + 8 * (blockIdx.y / NXB);
    const int cb  = blockIdx.y % NXB;
    if (rb >= 79) return;
    __shared__ _Float16 lds[16384];
    const int tid  = threadIdx.x;
    const int bm   = rb * 128, bn = cb * 128;
    const int w    = tid >> 6, lane = tid & 63;
    const int wr   = w >> 1,   wc   = w & 1;
    const int la   = lane & 15, g = lane >> 4;

    f32x4 acc[4][4] = {};

    const int srow = tid >> 3;
    const int skb0 = (tid & 7) * 16;

    for (int k0 = 0; k0 < Kp; k0 += 64) {
        __syncthreads();
#pragma unroll
        for (int i = 0; i < 4; i++) {
            int row = i * 32 + srow;
            int kb  = skb0 ^ ((row & 7) << 4);
            gload_lds(A + (size_t)(bm + row) * Kp + k0 + (kb >> 1),
                      lds + i * 2048 + w * 512);
        }
#pragma unroll
        for (int i = 0; i < 4; i++) {
            int row = i * 32 + srow;
            int kb  = skb0 ^ ((row & 7) << 4);
            gload_lds(B + (size_t)(bn + row) * Kp + k0 + (kb >> 1),
                      lds + 8192 + i * 2048 + w * 512);
        }
        asm volatile("s_waitcnt vmcnt(0)");
        __syncthreads();
#pragma unroll
        for (int s = 0; s < 2; s++) {
            f16x8 af[4], bf[4];
#pragma unroll
            for (int m = 0; m < 4; m++) {
                int r  = wr * 64 + m * 16 + la;
                int bc = (s * 64 + g * 16) ^ ((r & 7) << 4);
                af[m] = *(const f16x8*)(lds + r * 64 + (bc >> 1));
            }
#pragma unroll
            for (int n = 0; n < 4; n++) {
                int r  = wc * 64 + n * 16 + la;
                int bc = (s * 64 + g * 16) ^ ((r & 7) << 4);
                bf[n] = *(const f16x8*)(lds + 8192 + r * 64 + (bc >> 1));
            }
#pragma unroll
            for (int m = 0; m < 4; m++)
#pragma unroll
                for (int n = 0; n < 4; n++)
                    acc[m][n] = __builtin_amdgcn_mfma_f32_16x16x32_f16(af[m], bf[n], acc[m][n], 0, 0, 0);
        }
    }
#pragma unroll
    for (int m = 0; m < 4; m++) {
#pragma unroll
        for (int n = 0; n < 4; n++) {
            int col = bn + wc * 64 + n * 16 + la;
            if (col >= Nn) continue;
#pragma unroll
            for (int r = 0; r < 4; r++) {
                int row = bm + wr * 64 + m * 16 + g * 4 + r;
                if (row < M) C[(size_t)row * ldc + col] = (_Float16)acc[m][n][r];
            }
        }
    }
}

// ---------------- attn for H=4, HC=1024: one wave per node ----------------
__global__ __launch_bounds__(256) void attn4(const _Float16* __restrict__ h,
        const float* __restrict__ a_s, const float* __restrict__ a_d,
        float* __restrict__ esrc, float* __restrict__ edst) {
    const int w = threadIdx.x >> 6, lane = threadIdx.x & 63;
    const int node = blockIdx.x * 4 + w;
    const _Float16* row = h + (size_t)node * 1024;
    float ps[4], pd[4];
#pragma unroll
    for (int j = 0; j < 4; j++) {
        int c0 = j * 256 + lane * 4;
        f16x4 v = *(const f16x4*)(row + c0);
        float4 sa = *(const float4*)(a_s + c0);
        float4 da = *(const float4*)(a_d + c0);
        ps[j] = (float)v[0] * sa.x + (float)v[1] * sa.y + (float)v[2] * sa.z + (float)v[3] * sa.w;
        pd[j] = (float)v[0] * da.x + (float)v[1] * da.y + (float)v[2] * da.z + (float)v[3] * da.w;
    }
#pragma unroll
    for (int j = 0; j < 4; j++) {
#pragma unroll
        for (int off = 32; off; off >>= 1) {
            ps[j] += __shfl_xor(ps[j], off);
            pd[j] += __shfl_xor(pd[j], off);
        }
    }
    if (lane == 0) {
        *(float4*)(esrc + (size_t)node * 4) = make_float4(ps[0], ps[1], ps[2], ps[3]);
        *(float4*)(edst + (size_t)node * 4) = make_float4(pd[0], pd[1], pd[2], pd[3]);
    }
}

// ---------------- attn for layer 3 (padded head stride 128): one wave per node ----------------
__global__ __launch_bounds__(256) void attn6(const _Float16* __restrict__ h,
        const float* __restrict__ asp, const float* __restrict__ adp,
        float* __restrict__ esrc, float* __restrict__ edst) {
    const int w = threadIdx.x >> 6, lane = threadIdx.x & 63;
    const int node = blockIdx.x * 4 + w;
    const _Float16* row = h + (size_t)node * 768;
    float ps[3], pd[3];
#pragma unroll
    for (int j = 0; j < 3; j++) {
        int c0 = j * 256 + lane * 4;   // head = 2j + (lane>=32)
        f16x4 v = *(const f16x4*)(row + c0);
        float4 sa = *(const float4*)(asp + c0);
        float4 da = *(const float4*)(adp + c0);
        ps[j] = (float)v[0] * sa.x + (float)v[1] * sa.y + (float)v[2] * sa.z + (float)v[3] * sa.w;
        pd[j] = (float)v[0] * da.x + (float)v[1] * da.y + (float)v[2] * da.z + (float)v[3] * da.w;
    }
#pragma unroll
    for (int j = 0; j < 3; j++) {
#pragma unroll
        for (int off = 16; off; off >>= 1) {
            ps[j] += __shfl_xor(ps[j], off);
            pd[j] += __shfl_xor(pd[j], off);
        }
    }
    if (lane == 0 || lane == 32) {
        int hb = lane >> 5;
        float* es = esrc + (size_t)node * 6;
        float* ed = edst + (size_t)node * 6;
#pragma unroll
        for (int j = 0; j < 3; j++) { es[2 * j + hb] = ps[j]; ed[2 * j + hb] = pd[j]; }
    }
}

// ---------------- softmax alphas: wave per dst, SoA packed {src:u16, alpha:f16} ----------------
template<int H>
__global__ __launch_bounds__(256) void alpha_kernel(const float* __restrict__ esrc,
        const float* __restrict__ edst, const int* __restrict__ rowptr,
        const int* __restrict__ perm, unsigned int* __restrict__ pack) {
    const int w = threadIdx.x >> 6, lane = threadIdx.x & 63;
    const int d = blockIdx.x * 4 + w;
    int r0 = rowptr[d];
    int deg = rowptr[d + 1] - r0; if (deg > MAXDEG) deg = MAXDEG;
    float ed[H];
#pragma unroll
    for (int j = 0; j < H; j++) ed[j] = edst[(size_t)d * H + j];
    int s0 = 0, s1 = 0;
    float e0[H], e1[H];
    const bool a0v = lane < deg, a1v = lane + 64 < deg;
    if (a0v) {
        s0 = perm[r0 + lane];
        const float* pe = esrc + (size_t)s0 * H;
#pragma unroll
        for (int j = 0; j < H; j++) e0[j] = leaky(pe[j] + ed[j]);
    }
    if (a1v) {
        s1 = perm[r0 + lane + 64];
        const float* pe = esrc + (size_t)s1 * H;
#pragma unroll
        for (int j = 0; j < H; j++) e1[j] = leaky(pe[j] + ed[j]);
    }
#pragma unroll
    for (int j = 0; j < H; j++) {
        float m = fmaxf(a0v ? e0[j] : -1e30f, a1v ? e1[j] : -1e30f);
#pragma unroll
        for (int off = 32; off; off >>= 1) m = fmaxf(m, __shfl_xor(m, off));
        float x0 = a0v ? __expf(e0[j] - m) : 0.f;
        float x1 = a1v ? __expf(e1[j] - m) : 0.f;
        float ss = x0 + x1;
#pragma unroll
        for (int off = 32; off; off >>= 1) ss += __shfl_xor(ss, off);
        float inv = 1.f / fmaxf(ss, 1e-16f);
        e0[j] = x0 * inv; e1[j] = x1 * inv;
    }
    if (a0v) {
#pragma unroll
        for (int j = 0; j < H; j++) pack[(size_t)j * E_TOT + r0 + lane] = pack_as(e0[j], s0);
    }
    if (a1v) {
#pragma unroll
        for (int j = 0; j < H; j++) pack[(size_t)j * E_TOT + r0 + lane + 64] = pack_as(e1[j], s1);
    }
}

// ---------------- XCD-sliced gather (round-12 best): 16 lanes x f16x8, 4 par x 2 ser dsts ----
// grid(8, 313) x 256 threads: block covers dsts [by*32, by*32+32), guard d<N.
template<int RES>
__global__ __launch_bounds__(256) void agg_slice2(const _Float16* __restrict__ h,
        const unsigned int* __restrict__ pack, const int* __restrict__ rowptr,
        const float* __restrict__ bias, _Float16* __restrict__ xh) {
    const int s = blockIdx.x;
    const int w = threadIdx.x >> 6, lane = threadIdx.x & 63;
    const int g = lane >> 4, sl = lane & 15;
    const int col = s * 128 + sl * 8;
    const int hh = s >> 1;
    const unsigned int* packh = pack + (size_t)hh * E_TOT;
    f32x4 bv0 = *(const f32x4*)(bias + col);
    f32x4 bv1 = *(const f32x4*)(bias + col + 4);
    const int dbase = blockIdx.y * 32 + w * 8 + g;
#pragma unroll
    for (int it = 0; it < 2; it++) {
        const int d = dbase + it * 4;
        if (d >= N_NODES) continue;
        int r0 = rowptr[d];
        int deg = rowptr[d + 1] - r0; if (deg > MAXDEG) deg = MAXDEG;
        const unsigned int* pp = packh + r0;
        float acc[8] = {};
#pragma unroll 4
        for (int t = 0; t < deg; t++) {
            unsigned int p = pp[t];
            int src = p & 0xFFFF;
            float a = unpack_a(p);
            f16x8 v = *(const f16x8*)(h + (size_t)src * 1024 + col);
#pragma unroll
            for (int j = 0; j < 8; j++) acc[j] = fmaf(a, (float)v[j], acc[j]);
        }
        size_t o = (size_t)d * 1024 + col;
        float vv[8];
        vv[0] = acc[0] + bv0[0]; vv[1] = acc[1] + bv0[1];
        vv[2] = acc[2] + bv0[2]; vv[3] = acc[3] + bv0[3];
        vv[4] = acc[4] + bv1[0]; vv[5] = acc[5] + bv1[1];
        vv[6] = acc[6] + bv1[2]; vv[7] = acc[7] + bv1[3];
        if (RES) {
            f16x8 rv = *(const f16x8*)(xh + o);
#pragma unroll
            for (int j = 0; j < 8; j++) vv[j] += (float)rv[j];
        }
        f16x8 hv;
#pragma unroll
        for (int j = 0; j < 8; j++) {
            float u = vv[j];
            u = (u > 0.f) ? u : expm1f(u);
            hv[j] = (_Float16)u;
        }
        *(f16x8*)(xh + o) = hv;
    }
}

// ---------------- layer-3 sliced gather: grid(8,313), slices 6,7 idle ----------------
__global__ __launch_bounds__(256) void agg_slice3(const _Float16* __restrict__ h,
        const unsigned int* __restrict__ pack, const int* __restrict__ rowptr,
        _Float16* __restrict__ obuf) {
    const int s = blockIdx.x;               // == head; 6,7 idle
    if (s >= 6) return;
    const int w = threadIdx.x >> 6, lane = threadIdx.x & 63;
    const int g = lane >> 4, sl = lane & 15;
    const int col = s * 128 + sl * 8;
    const unsigned int* packh = pack + (size_t)s * E_TOT;
    const int dbase = blockIdx.y * 32 + w * 8 + g;
#pragma unroll
    for (int it = 0; it < 2; it++) {
        const int d = dbase + it * 4;
        if (d >= N_NODES) continue;
        int r0 = rowptr[d];
        int deg = rowptr[d + 1] - r0; if (deg > MAXDEG) deg = MAXDEG;
        const unsigned int* pp = packh + r0;
        float acc[8] = {};
#pragma unroll 4
        for (int t = 0; t < deg; t++) {
            unsigned int p = pp[t];
            int src = p & 0xFFFF;
            float a = unpack_a(p);
            f16x8 v = *(const f16x8*)(h + (size_t)src * 768 + col);
#pragma unroll
            for (int j = 0; j < 8; j++) acc[j] = fmaf(a, (float)v[j], acc[j]);
        }
        f16x8 hv;
#pragma unroll
        for (int j = 0; j < 8; j++) hv[j] = (_Float16)acc[j];
        *(f16x8*)(obuf + (size_t)d * 768 + col) = hv;
    }
}

// ---------------- final head-mean + bias + sigmoid ----------------
__global__ void finish_kernel(const _Float16* __restrict__ obuf,
                              const float* __restrict__ b3, float* __restrict__ out) {
    int i = blockIdx.x * 256 + threadIdx.x;
    if (i >= N_NODES * 121) return;
    int d = i / 121, cc = i - d * 121;
    float ssum = 0.f;
#pragma unroll
    for (int hh = 0; hh < 6; hh++) ssum += (float)obuf[(size_t)d * 768 + hh * 128 + cc];
    float sres = ssum * (1.f / 6.f) + b3[cc];
    out[i] = 1.f / (1.f + __expf(-sres));
}

// ---------------- launcher ----------------
extern "C" void kernel_launch(void* const* d_in, const int* in_sizes, int n_in,
                              void* d_out, int out_size, void* d_ws, size_t ws_size,
                              hipStream_t stream) {
    const float* x   = (const float*)d_in[0];
    const int*   ei  = (const int*)d_in[1];
    const float* W1  = (const float*)d_in[2];
    const float* as1 = (const float*)d_in[3];
    const float* ad1 = (const float*)d_in[4];
    const float* b1  = (const float*)d_in[5];
    const float* W2  = (const float*)d_in[6];
    const float* as2 = (const float*)d_in[7];
    const float* ad2 = (const float*)d_in[8];
    const float* b2  = (const float*)d_in[9];
    const float* W3  = (const float*)d_in[10];
    const float* as3 = (const float*)d_in[11];
    const float* ad3 = (const float*)d_in[12];
    const float* b3  = (const float*)d_in[13];
    float* out = (float*)d_out;

    float* fws  = (float*)d_ws;
    float* esrc = fws;                       // N*6
    float* edst = fws + 60000;               // N*6
    float* asp  = fws + 120000;              // 768
    float* adp  = fws + 120768;              // 768
    unsigned int* pack = (unsigned int*)(fws + 121536);  // 6 * E_TOT u32
    int*   iws  = (int*)(fws + 121536 + 6 * E_TOT);
    int* deg    = iws;                       // N
    int* rowptr = iws + N_NODES;             // N+1
    int* cursor = iws + 2 * N_NODES + 1;     // N
    int* perm   = iws + 3 * N_NODES + 1;     // E_TOT
    _Float16* f16b = (_Float16*)(iws + 3 * N_NODES + 1 + E_TOT + 3);
    _Float16* xh   = f16b;                          // MPAD*1024
    _Float16* xh1  = xh + (size_t)MPAD * 1024;      // MPAD*64
    _Float16* W1h  = xh1 + (size_t)MPAD * 64;       // 1024*64
    _Float16* W2h  = W1h + 1024 * 64;               // 1024*1024
    _Float16* W3p  = W2h + 1024 * 1024;             // 768*1024 (head-padded)
    _Float16* h16  = W3p + 768 * 1024;              // MPAD*1024
    _Float16* obuf = h16 + (size_t)MPAD * 1024;     // N*768

    hipMemsetAsync(deg, 0, N_NODES * sizeof(int), stream);
    count_kernel<<<(E_TOT + 255) / 256, 256, 0, stream>>>(ei, deg);
    scan_kernel<<<1, 1024, 0, stream>>>(deg, rowptr, cursor);
    scatter_kernel<<<(E_TOT + 255) / 256, 256, 0, stream>>>(ei, cursor, perm);

    dim3 blk(256);
    cvt_all<<<(CVT_TOTAL + 255) / 256, blk, 0, stream>>>(x, W1, W2, W3, as3, ad3,
                                                          xh1, W1h, W2h, W3p, asp, adp, xh);

    // ---- layer 1: K=50->64, H=4, C=256 ----
    {
        gemm_mfma<<<dim3(8, 80), blk, 0, stream>>>(xh1, W1h, h16, N_NODES, 1024, 64, 1024);
        attn4<<<N_NODES / 4, blk, 0, stream>>>(h16, as1, ad1, esrc, edst);
        alpha_kernel<4><<<N_NODES / 4, blk, 0, stream>>>(esrc, edst, rowptr, perm, pack);
        agg_slice2<0><<<dim3(8, 313), blk, 0, stream>>>(h16, pack, rowptr, b1, xh);
    }
    // ---- layer 2: K=1024, H=4, C=256, residual ----
    {
        gemm_mfma<<<dim3(8, 80), blk, 0, stream>>>(xh, W2h, h16, N_NODES, 1024, 1024, 1024);
        attn4<<<N_NODES / 4, blk, 0, stream>>>(h16, as2, ad2, esrc, edst);
        alpha_kernel<4><<<N_NODES / 4, blk, 0, stream>>>(esrc, edst, rowptr, perm, pack);
        agg_slice2<1><<<dim3(8, 313), blk, 0, stream>>>(h16, pack, rowptr, b2, xh);
    }
    // ---- layer 3: K=1024, H=6, C=121 (padded 128), mean heads + sigmoid ----
    {
        gemm_mfma<<<dim3(8, 60), blk, 0, stream>>>(xh, W3p, h16, N_NODES, 768, 1024, 768);
        attn6<<<N_NODES / 4, blk, 0, stream>>>(h16, asp, adp, esrc, edst);
        alpha_kernel<6><<<N_NODES / 4, blk, 0, stream>>>(esrc, edst, rowptr, perm, pack);
        agg_slice3<<<dim3(8, 313), blk, 0, stream>>>(h16, pack, rowptr, obuf);
        finish_kernel<<<(N_NODES * 121 + 255) / 256, blk, 0, stream>>>(obuf, b3, out);
    }
}